// Round 11
// baseline (53.129 us; speedup 1.0000x reference)
//
#include <hip/hip_runtime.h>
#include <math.h>

#define NEGV  (-1e30f)
#define LOG2E 1.44269504088896340736f
#define LN2   0.69314718055994530942f

typedef __attribute__((ext_vector_type(8))) _Float16 half8;
typedef __attribute__((ext_vector_type(2))) __fp16   fp16x2;  // cvt_pkrtz return type
typedef __attribute__((ext_vector_type(4))) float f32x4;

// Single-instruction base-2 transcendentals (v_exp_f32 / v_log_f32).
__device__ __forceinline__ float exp2_fast(float a) { return __builtin_amdgcn_exp2f(a); }
__device__ __forceinline__ float log2_fast(float a) { return __builtin_amdgcn_logf(a); }

// 8 fp32 -> 8 fp16 via v_cvt_pkrtz (4 VALU ops).
__device__ __forceinline__ half8 cvt8(float4 a, float4 b) {
    union { half8 v; fp16x2 p[4]; } u;
    u.p[0] = __builtin_amdgcn_cvt_pkrtz(a.x, a.y);
    u.p[1] = __builtin_amdgcn_cvt_pkrtz(a.z, a.w);
    u.p[2] = __builtin_amdgcn_cvt_pkrtz(b.x, b.y);
    u.p[3] = __builtin_amdgcn_cvt_pkrtz(b.z, b.w);
    return u.v;
}

// ws layout (floats): [0..63] wg_full[g] = (mw[g]-logZ)*LOG2E
//                     [64..] theta fp16 frags: slot s = gt*2+kt (8 slots),
//                            addr = 64 + (s*64 + lane)*4   (half8 = 4 floats)
#define WS_FLOATS_NEEDED (64 + 8 * 64 * 4)

__global__ void prep_kernel(const float* __restrict__ theta,
                            const float* __restrict__ mw,
                            float* __restrict__ ws)
{
    const int lane = threadIdx.x;  // 64 threads, 1 wave
    const int c15  = lane & 15;
    const int q    = lane >> 4;

    const float v = mw[lane];
    float m = v;
#pragma unroll
    for (int s = 32; s >= 1; s >>= 1) m = fmaxf(m, __shfl_xor(m, s, 64));
    float e = __expf(v - m);
#pragma unroll
    for (int s = 32; s >= 1; s >>= 1) e += __shfl_xor(e, s, 64);
    const float logZ = m + __logf(e);
    ws[lane] = (v - logZ) * LOG2E;

#pragma unroll
    for (int gt = 0; gt < 4; ++gt) {
        const float* tr = theta + (size_t)((gt << 4) + c15) * 64 + (q << 3);
#pragma unroll
        for (int kt = 0; kt < 2; ++kt) {
            float4 a = *(const float4*)(tr + kt * 32);
            float4 c = *(const float4*)(tr + kt * 32 + 4);
            a.x *= LOG2E; a.y *= LOG2E; a.z *= LOG2E; a.w *= LOG2E;
            c.x *= LOG2E; c.y *= LOG2E; c.z *= LOG2E; c.w *= LOG2E;
            const half8 h = cvt8(a, c);
            const int s = (gt << 1) + kt;
            *(half8*)&ws[64 + ((size_t)(s * 64 + lane)) * 4] = h;
        }
    }
}

// One block = one batch, 4 waves.
// NEW decomposition: wave w owns l in [32w, 32w+32) (2 l-tiles) x ALL 64 g.
// B-fragments (x rows) load DIRECTLY from global (R2-verified mapping:
// row = lt*16 + c15, k-octet = q*8 -> 16 rows x 128 B dense per instr);
// A-fragments (theta, all 8 slots) from ws registers. NO x staging in LDS.
// Phase 1 (lse over l, per g) is cross-wave: per-lane partials -> lds_p
// (64 rows x 272 B odd-quad stride) -> transposed re-reduce (4 thr/g) -> c4.
// Phase 2 (lse over g, per l) is wave-local: in-lane 16 + shfl {16,32},
// output written directly (no reduction buffer, no epilogue phase).
template<bool USE_WS>
__global__ __launch_bounds__(256, 4) void mixed_logit_kernel(
    const float* __restrict__ x,      // [B,128,64]
    const int*   __restrict__ lens,   // [B]
    const float* __restrict__ theta,  // [64,64]
    const float* __restrict__ mw,     // [64]
    const float* __restrict__ ws,     // prep output (if USE_WS)
    float* __restrict__ out)          // [B,128]
{
    __shared__ __align__(16) unsigned char lds_p[64 * 272];  // 17408 B
    __shared__ __align__(16) float lds_c[64];                // c4 per g

    const int tid  = threadIdx.x;
    const int lane = tid & 63;
    const int w    = tid >> 6;
    const int c15  = lane & 15;
    const int q    = lane >> 4;
    const int b    = blockIdx.x;
    const int len  = lens[b];

    // ---- theta A-fragments, ALL 8 slots (4 g-tiles x 2 k-tiles) ----
    half8 th[4][2];
    float logZ_fb = 0.f;   // fallback-only
    if constexpr (USE_WS) {
#pragma unroll
        for (int gt = 0; gt < 4; ++gt)
#pragma unroll
            for (int kt = 0; kt < 2; ++kt)
                th[gt][kt] = *(const half8*)&ws[64 + ((size_t)((((gt << 1) + kt) * 64) + lane)) * 4];
    } else {
#pragma unroll
        for (int gt = 0; gt < 4; ++gt) {
            const float* tr = theta + (size_t)((gt << 4) + c15) * 64 + (q << 3);
#pragma unroll
            for (int kt = 0; kt < 2; ++kt) {
                float4 a = *(const float4*)(tr + kt * 32);
                float4 c = *(const float4*)(tr + kt * 32 + 4);
                a.x *= LOG2E; a.y *= LOG2E; a.z *= LOG2E; a.w *= LOG2E;
                c.x *= LOG2E; c.y *= LOG2E; c.z *= LOG2E; c.w *= LOG2E;
                th[gt][kt] = cvt8(a, c);
            }
        }
        const float mwl = mw[lane];
        float mmax = mwl;
#pragma unroll
        for (int s = 32; s >= 1; s >>= 1) mmax = fmaxf(mmax, __shfl_xor(mmax, s, 64));
        float me = __expf(mwl - mmax);
#pragma unroll
        for (int s = 32; s >= 1; s >>= 1) me += __shfl_xor(me, s, 64);
        logZ_fb = mmax + __logf(me);
    }

    // ---- x B-fragments direct from global (dense 16-row x 128B per instr) ----
    half8 xf[2][2];
    {
        const float* xb = x + (size_t)b * 8192;
#pragma unroll
        for (int lt_loc = 0; lt_loc < 2; ++lt_loc) {
            const int row = (w << 5) + (lt_loc << 4) + c15;
#pragma unroll
            for (int kt = 0; kt < 2; ++kt) {
                const float* p = xb + (size_t)row * 64 + kt * 32 + (q << 3);
                xf[lt_loc][kt] = cvt8(*(const float4*)p, *(const float4*)(p + 4));
            }
        }
    }

    // ---- GEMM: 4 g-tiles x 2 l-tiles x 2 k-tiles = 16 MFMA ----
    f32x4 acc[4][2];
#pragma unroll
    for (int gt = 0; gt < 4; ++gt)
#pragma unroll
        for (int lt = 0; lt < 2; ++lt) acc[gt][lt] = (f32x4){0.f, 0.f, 0.f, 0.f};

#pragma unroll
    for (int gt = 0; gt < 4; ++gt)
#pragma unroll
        for (int lt = 0; lt < 2; ++lt)
#pragma unroll
            for (int kt = 0; kt < 2; ++kt)
                acc[gt][lt] = __builtin_amdgcn_mfma_f32_16x16x32_f16(th[gt][kt], xf[lt][kt], acc[gt][lt], 0, 0, 0);

    // ---- mask invalid l (exp2(NEGV + c4) == 0 exactly) ----
    {
        const int l0 = (w << 5) + c15;
        const bool v0 = l0 < len;
        const bool v1 = (l0 + 16) < len;
#pragma unroll
        for (int gt = 0; gt < 4; ++gt)
#pragma unroll
            for (int i = 0; i < 4; ++i) {
                acc[gt][0][i] = v0 ? acc[gt][0][i] : NEGV;
                acc[gt][1][i] = v1 ? acc[gt][1][i] : NEGV;
            }
    }

    // ---- phase 1 partials: p1[gt][i] = sum over my 2 l's of exp2(u) ----
    // write to lds_p row (w*16+c15), byte = row*272 + gt*64 + q*16
    {
        unsigned char* base = lds_p + ((w << 4) + c15) * 272 + (q << 4);
#pragma unroll
        for (int gt = 0; gt < 4; ++gt) {
            f32x4 p1;
#pragma unroll
            for (int i = 0; i < 4; ++i)
                p1[i] = exp2_fast(acc[gt][0][i]) + exp2_fast(acc[gt][1][i]);
            *(f32x4*)(base + (gt << 6)) = p1;
        }
    }
    __syncthreads();

    // ---- re-reduce: 4 threads per g sum 16 rows each (rotated, conflict-lite) ----
    {
        const int gg = (w << 4) + (lane >> 2);   // this thread's g
        const int r4 = lane & 3;
        float s = 0.f;
#pragma unroll
        for (int k = 0; k < 16; ++k) {
            const int rr = (r4 << 4) + ((k + (r4 << 2)) & 15);
            s += *(const float*)(lds_p + rr * 272 + (gg << 2));
        }
        s += __shfl_xor(s, 1, 64);
        s += __shfl_xor(s, 2, 64);
        if (r4 == 0) {
            float wgv;
            if constexpr (USE_WS) wgv = ws[gg];
            else                  wgv = (mw[gg] - logZ_fb) * LOG2E;
            lds_c[gg] = wgv - log2_fast(s);
        }
    }
    __syncthreads();

    // ---- phase 2: wave-local lse over 64 g per l; direct output ----
    {
        f32x4 c4[4];
#pragma unroll
        for (int gt = 0; gt < 4; ++gt)
            c4[gt] = *(const f32x4*)((const unsigned char*)lds_c + (gt << 6) + (q << 4));

#pragma unroll
        for (int lt = 0; lt < 2; ++lt) {
            float s2 = 0.f;
#pragma unroll
            for (int gt = 0; gt < 4; ++gt)
#pragma unroll
                for (int i = 0; i < 4; ++i)
                    s2 += exp2_fast(acc[gt][lt][i] + c4[gt][i]);
            s2 += __shfl_xor(s2, 16, 64);
            s2 += __shfl_xor(s2, 32, 64);
            if (q == 0) {
                const int l = (w << 5) + (lt << 4) + c15;
                out[(size_t)b * 128 + l] = (l < len) ? LN2 * log2_fast(s2) : NEGV;
            }
        }
    }
}

extern "C" void kernel_launch(void* const* d_in, const int* in_sizes, int n_in,
                              void* d_out, int out_size, void* d_ws, size_t ws_size,
                              hipStream_t stream) {
    const float* x     = (const float*)d_in[0];
    const int*   lens  = (const int*)d_in[1];
    const float* theta = (const float*)d_in[2];
    const float* mw    = (const float*)d_in[3];
    float* out = (float*)d_out;
    const int B = in_sizes[1];  // 8192

    if (ws_size >= (size_t)WS_FLOATS_NEEDED * sizeof(float)) {
        float* ws = (float*)d_ws;
        prep_kernel<<<1, 64, 0, stream>>>(theta, mw, ws);
        mixed_logit_kernel<true><<<B, 256, 0, stream>>>(x, lens, theta, mw, ws, out);
    } else {
        mixed_logit_kernel<false><<<B, 256, 0, stream>>>(x, lens, theta, mw, nullptr, out);
    }
}

// Round 12
// 51.428 us; speedup vs baseline: 1.0331x; 1.0331x over previous
//
#include <hip/hip_runtime.h>
#include <math.h>

#define NEGV  (-1e30f)
#define LOG2E 1.44269504088896340736f
#define LN2   0.69314718055994530942f

typedef __attribute__((ext_vector_type(8))) _Float16 half8;
typedef __attribute__((ext_vector_type(2))) __fp16   fp16x2;  // cvt_pkrtz return type
typedef __attribute__((ext_vector_type(4))) float f32x4;

// Single-instruction base-2 transcendentals (v_exp_f32 / v_log_f32).
__device__ __forceinline__ float exp2_fast(float a) { return __builtin_amdgcn_exp2f(a); }
__device__ __forceinline__ float log2_fast(float a) { return __builtin_amdgcn_logf(a); }

// 8 fp32 -> 8 fp16 via v_cvt_pkrtz (4 VALU ops).
__device__ __forceinline__ half8 cvt8(float4 a, float4 b) {
    union { half8 v; fp16x2 p[4]; } u;
    u.p[0] = __builtin_amdgcn_cvt_pkrtz(a.x, a.y);
    u.p[1] = __builtin_amdgcn_cvt_pkrtz(a.z, a.w);
    u.p[2] = __builtin_amdgcn_cvt_pkrtz(b.x, b.y);
    u.p[3] = __builtin_amdgcn_cvt_pkrtz(b.z, b.w);
    return u.v;
}

// ws layout (floats): [0..63] wg_full[g] = (mw[g]-logZ)*LOG2E
//                     [64..] theta fp16 frags: slot s = gt*2+kt (8 slots),
//                            addr = 64 + (s*64 + lane)*4   (half8 = 4 floats)
#define WS_FLOATS_NEEDED (64 + 8 * 64 * 4)

__global__ void prep_kernel(const float* __restrict__ theta,
                            const float* __restrict__ mw,
                            float* __restrict__ ws)
{
    const int lane = threadIdx.x;  // 64 threads, 1 wave
    const int c15  = lane & 15;
    const int q    = lane >> 4;

    const float v = mw[lane];
    float m = v;
#pragma unroll
    for (int s = 32; s >= 1; s >>= 1) m = fmaxf(m, __shfl_xor(m, s, 64));
    float e = __expf(v - m);
#pragma unroll
    for (int s = 32; s >= 1; s >>= 1) e += __shfl_xor(e, s, 64);
    const float logZ = m + __logf(e);
    ws[lane] = (v - logZ) * LOG2E;

#pragma unroll
    for (int gt = 0; gt < 4; ++gt) {
        const float* tr = theta + (size_t)((gt << 4) + c15) * 64 + (q << 3);
#pragma unroll
        for (int kt = 0; kt < 2; ++kt) {
            float4 a = *(const float4*)(tr + kt * 32);
            float4 c = *(const float4*)(tr + kt * 32 + 4);
            a.x *= LOG2E; a.y *= LOG2E; a.z *= LOG2E; a.w *= LOG2E;
            c.x *= LOG2E; c.y *= LOG2E; c.z *= LOG2E; c.w *= LOG2E;
            const half8 h = cvt8(a, c);
            const int s = (gt << 1) + kt;
            *(half8*)&ws[64 + ((size_t)(s * 64 + lane)) * 4] = h;
        }
    }
}

// One block = one batch, 4 waves.
// Decomposition (R11, verified): wave w owns l in [32w,32w+32) x ALL 64 g.
// Fragment source (R10, verified): x staged in LDS as fp16, coalesced global
// float4 loads; row stride 144 B (9x16B odd -> conflict-free-floor b128).
// KEY: staging is WAVE-LOCAL (wave w stages exactly its own 32 rows and only
// reads those) -> no barrier between stage and GEMM; waves run the whole
// load->cvt->MFMA->exp2 front desynchronized. Only 2 barriers, both late.
// Phase 1 (lse over l, per g): per-lane partials -> lds_p (rows = w*16+c15,
// stride 272 B) -> transposed re-reduce (4 thr/g, rotated) -> lds_c[g].
// Phase 2 (lse over g, per l): wave-local, in-lane 16 + shfl {16,32} -> out.
template<bool USE_WS>
__global__ __launch_bounds__(256, 4) void mixed_logit_kernel(
    const float* __restrict__ x,      // [B,128,64]
    const int*   __restrict__ lens,   // [B]
    const float* __restrict__ theta,  // [64,64]
    const float* __restrict__ mw,     // [64]
    const float* __restrict__ ws,     // prep output (if USE_WS)
    float* __restrict__ out)          // [B,128]
{
    __shared__ __align__(16) unsigned char xbuf[128 * 144];  // 18432 B
    __shared__ __align__(16) unsigned char lds_p[64 * 272];  // 17408 B
    __shared__ __align__(16) float lds_c[64];                // c4 per g

    const int tid  = threadIdx.x;
    const int lane = tid & 63;
    const int w    = tid >> 6;
    const int c15  = lane & 15;
    const int q    = lane >> 4;
    const int b    = blockIdx.x;
    const int len  = lens[b];

    // ---- theta A-fragments, ALL 8 slots (4 g-tiles x 2 k-tiles) ----
    half8 th[4][2];
    float logZ_fb = 0.f;   // fallback-only
    if constexpr (USE_WS) {
#pragma unroll
        for (int gt = 0; gt < 4; ++gt)
#pragma unroll
            for (int kt = 0; kt < 2; ++kt)
                th[gt][kt] = *(const half8*)&ws[64 + ((size_t)((((gt << 1) + kt) * 64) + lane)) * 4];
    } else {
#pragma unroll
        for (int gt = 0; gt < 4; ++gt) {
            const float* tr = theta + (size_t)((gt << 4) + c15) * 64 + (q << 3);
#pragma unroll
            for (int kt = 0; kt < 2; ++kt) {
                float4 a = *(const float4*)(tr + kt * 32);
                float4 c = *(const float4*)(tr + kt * 32 + 4);
                a.x *= LOG2E; a.y *= LOG2E; a.z *= LOG2E; a.w *= LOG2E;
                c.x *= LOG2E; c.y *= LOG2E; c.z *= LOG2E; c.w *= LOG2E;
                th[gt][kt] = cvt8(a, c);
            }
        }
        const float mwl = mw[lane];
        float mmax = mwl;
#pragma unroll
        for (int s = 32; s >= 1; s >>= 1) mmax = fmaxf(mmax, __shfl_xor(mmax, s, 64));
        float me = __expf(mwl - mmax);
#pragma unroll
        for (int s = 32; s >= 1; s >>= 1) me += __shfl_xor(me, s, 64);
        logZ_fb = mmax + __logf(me);
    }

    // ---- wave-local stage: rows [32w, 32w+32), coalesced, no barrier ----
    {
        const float* xb = x + (size_t)b * 8192;
#pragma unroll
        for (int i = 0; i < 4; ++i) {
            const int row = (w << 5) + (i << 3) + (lane >> 3);  // own rows only
            const int p8  = lane & 7;
            const float* p = xb + (size_t)row * 64 + (p8 << 3);
            const half8 h = cvt8(*(const float4*)p, *(const float4*)(p + 4));
            *(half8*)(xbuf + row * 144 + p8 * 16) = h;
        }
    }

    // ---- x B-fragments from own LDS rows (wave-internal lgkmcnt ordering) ----
    half8 xf[2][2];
#pragma unroll
    for (int lt = 0; lt < 2; ++lt) {
        const int row = (w << 5) + (lt << 4) + c15;
#pragma unroll
        for (int kt = 0; kt < 2; ++kt)
            xf[lt][kt] = *(const half8*)(xbuf + row * 144 + kt * 64 + (q << 4));
    }

    // ---- GEMM: 4 g-tiles x 2 l-tiles x 2 k-tiles = 16 MFMA ----
    f32x4 acc[4][2];
#pragma unroll
    for (int gt = 0; gt < 4; ++gt)
#pragma unroll
        for (int lt = 0; lt < 2; ++lt) acc[gt][lt] = (f32x4){0.f, 0.f, 0.f, 0.f};

#pragma unroll
    for (int gt = 0; gt < 4; ++gt)
#pragma unroll
        for (int lt = 0; lt < 2; ++lt)
#pragma unroll
            for (int kt = 0; kt < 2; ++kt)
                acc[gt][lt] = __builtin_amdgcn_mfma_f32_16x16x32_f16(th[gt][kt], xf[lt][kt], acc[gt][lt], 0, 0, 0);

    // ---- mask invalid l (exp2(NEGV + c4) == 0 exactly) ----
    {
        const int l0 = (w << 5) + c15;
        const bool v0 = l0 < len;
        const bool v1 = (l0 + 16) < len;
#pragma unroll
        for (int gt = 0; gt < 4; ++gt)
#pragma unroll
            for (int i = 0; i < 4; ++i) {
                acc[gt][0][i] = v0 ? acc[gt][0][i] : NEGV;
                acc[gt][1][i] = v1 ? acc[gt][1][i] : NEGV;
            }
    }

    // ---- phase 1 partials: p1[gt][i] = sum over my 2 l's of exp2(u) ----
    {
        unsigned char* base = lds_p + ((w << 4) + c15) * 272 + (q << 4);
#pragma unroll
        for (int gt = 0; gt < 4; ++gt) {
            f32x4 p1;
#pragma unroll
            for (int i = 0; i < 4; ++i)
                p1[i] = exp2_fast(acc[gt][0][i]) + exp2_fast(acc[gt][1][i]);
            *(f32x4*)(base + (gt << 6)) = p1;
        }
    }
    __syncthreads();

    // ---- re-reduce: 4 threads per g sum 16 rows each (rotated, 2-way max) ----
    {
        const int gg = (w << 4) + (lane >> 2);   // this thread's g
        const int r4 = lane & 3;
        float s = 0.f;
#pragma unroll
        for (int k = 0; k < 16; ++k) {
            const int rr = (r4 << 4) + ((k + (r4 << 2)) & 15);
            s += *(const float*)(lds_p + rr * 272 + (gg << 2));
        }
        s += __shfl_xor(s, 1, 64);
        s += __shfl_xor(s, 2, 64);
        if (r4 == 0) {
            float wgv;
            if constexpr (USE_WS) wgv = ws[gg];
            else                  wgv = (mw[gg] - logZ_fb) * LOG2E;
            lds_c[gg] = wgv - log2_fast(s);
        }
    }
    __syncthreads();

    // ---- phase 2: wave-local lse over 64 g per l; direct output ----
    {
        f32x4 c4[4];
#pragma unroll
        for (int gt = 0; gt < 4; ++gt)
            c4[gt] = *(const f32x4*)((const unsigned char*)lds_c + (gt << 6) + (q << 4));

#pragma unroll
        for (int lt = 0; lt < 2; ++lt) {
            float s2 = 0.f;
#pragma unroll
            for (int gt = 0; gt < 4; ++gt)
#pragma unroll
                for (int i = 0; i < 4; ++i)
                    s2 += exp2_fast(acc[gt][lt][i] + c4[gt][i]);
            s2 += __shfl_xor(s2, 16, 64);
            s2 += __shfl_xor(s2, 32, 64);
            if (q == 0) {
                const int l = (w << 5) + (lt << 4) + c15;
                out[(size_t)b * 128 + l] = (l < len) ? LN2 * log2_fast(s2) : NEGV;
            }
        }
    }
}

extern "C" void kernel_launch(void* const* d_in, const int* in_sizes, int n_in,
                              void* d_out, int out_size, void* d_ws, size_t ws_size,
                              hipStream_t stream) {
    const float* x     = (const float*)d_in[0];
    const int*   lens  = (const int*)d_in[1];
    const float* theta = (const float*)d_in[2];
    const float* mw    = (const float*)d_in[3];
    float* out = (float*)d_out;
    const int B = in_sizes[1];  // 8192

    if (ws_size >= (size_t)WS_FLOATS_NEEDED * sizeof(float)) {
        float* ws = (float*)d_ws;
        prep_kernel<<<1, 64, 0, stream>>>(theta, mw, ws);
        mixed_logit_kernel<true><<<B, 256, 0, stream>>>(x, lens, theta, mw, ws, out);
    } else {
        mixed_logit_kernel<false><<<B, 256, 0, stream>>>(x, lens, theta, mw, nullptr, out);
    }
}

// Round 13
// 49.113 us; speedup vs baseline: 1.0818x; 1.0471x over previous
//
#include <hip/hip_runtime.h>
#include <math.h>

#define NEGV  (-1e30f)
#define LOG2E 1.44269504088896340736f
#define LN2   0.69314718055994530942f

typedef __attribute__((ext_vector_type(8))) _Float16 half8;
typedef __attribute__((ext_vector_type(2))) __fp16   fp16x2;  // cvt_pkrtz return type
typedef __attribute__((ext_vector_type(4))) float f32x4;

// Single-instruction base-2 transcendentals (v_exp_f32 / v_log_f32).
__device__ __forceinline__ float exp2_fast(float a) { return __builtin_amdgcn_exp2f(a); }
__device__ __forceinline__ float log2_fast(float a) { return __builtin_amdgcn_logf(a); }

// 8 fp32 -> 8 fp16 via v_cvt_pkrtz (4 VALU ops).
__device__ __forceinline__ half8 cvt8(float4 a, float4 b) {
    union { half8 v; fp16x2 p[4]; } u;
    u.p[0] = __builtin_amdgcn_cvt_pkrtz(a.x, a.y);
    u.p[1] = __builtin_amdgcn_cvt_pkrtz(a.z, a.w);
    u.p[2] = __builtin_amdgcn_cvt_pkrtz(b.x, b.y);
    u.p[3] = __builtin_amdgcn_cvt_pkrtz(b.z, b.w);
    return u.v;
}

// ws layout (floats): [0..63] wg_full[g] = (mw[g]-logZ)*LOG2E
//                     [64..] theta fp16 frags: slot s = w*2+kt (8 slots),
//                            addr = 64 + (s*64 + lane)*4   (half8 = 4 floats)
#define WS_FLOATS_NEEDED (64 + 8 * 64 * 4)

__global__ void prep_kernel(const float* __restrict__ theta,
                            const float* __restrict__ mw,
                            float* __restrict__ ws)
{
    const int lane = threadIdx.x;  // 64 threads, 1 wave
    const int c15  = lane & 15;
    const int q    = lane >> 4;

    const float v = mw[lane];
    float m = v;
#pragma unroll
    for (int s = 32; s >= 1; s >>= 1) m = fmaxf(m, __shfl_xor(m, s, 64));
    float e = __expf(v - m);
#pragma unroll
    for (int s = 32; s >= 1; s >>= 1) e += __shfl_xor(e, s, 64);
    const float logZ = m + __logf(e);
    ws[lane] = (v - logZ) * LOG2E;

#pragma unroll
    for (int w = 0; w < 4; ++w) {
        const float* tr = theta + (size_t)((w << 4) + c15) * 64 + (q << 3);
#pragma unroll
        for (int kt = 0; kt < 2; ++kt) {
            float4 a = *(const float4*)(tr + kt * 32);
            float4 c = *(const float4*)(tr + kt * 32 + 4);
            a.x *= LOG2E; a.y *= LOG2E; a.z *= LOG2E; a.w *= LOG2E;
            c.x *= LOG2E; c.y *= LOG2E; c.z *= LOG2E; c.w *= LOG2E;
            const half8 h = cvt8(a, c);
            const int s = (w << 1) + kt;
            *(half8*)&ws[64 + ((size_t)(s * 64 + lane)) * 4] = h;
        }
    }
}

// R10 structure (best measured): one block = one batch, 4 waves; wave w owns
// g in [16w,16w+16), all 128 l. x staged once in LDS as fp16 (row stride
// 144 B = 9x16B odd -> conflict-free-floor b128). Single fp16 MFMA per K-tile.
// Log2-domain softmax, no max subtraction (bounded utilities; masked slots
// give exp2 == 0 exactly).
// NEW vs R10: exp2-reuse -- p = exp2(acc) computed once (phase 1), phase 2 is
// s2 = sum_i p[nt][i] * e4[i] with e4[i] = exp2(c4[i]) (4 exp2 instead of 32).
// x global loads issued FIRST so HBM requests start before theta/ws reads.
template<bool USE_WS>
__global__ __launch_bounds__(256, 6) void mixed_logit_kernel(
    const float* __restrict__ x,      // [B,128,64]
    const int*   __restrict__ lens,   // [B]
    const float* __restrict__ theta,  // [64,64]
    const float* __restrict__ mw,     // [64]
    const float* __restrict__ ws,     // prep output (if USE_WS)
    float* __restrict__ out)          // [B,128]
{
    __shared__ __align__(16) unsigned char xbuf[128 * 144];  // 18432 B
    __shared__ float red_s[4][128];                          // 2 KB

    const int tid  = threadIdx.x;
    const int lane = tid & 63;
    const int w    = tid >> 6;
    const int c15  = lane & 15;
    const int q    = lane >> 4;
    const int b    = blockIdx.x;
    const int len  = lens[b];

    // ---- x loads first: 8 coalesced float4 loads/thread (HBM starts now) ----
    float4 ra[8];
    {
        const float4* xp = (const float4*)(x + (size_t)b * 8192);
#pragma unroll
        for (int i = 0; i < 4; ++i) {
            const int j2 = (i << 8) + tid;
            ra[2 * i]     = xp[j2 * 2];
            ra[2 * i + 1] = xp[j2 * 2 + 1];
        }
    }

    // ---- theta fragments + mixture constants (L2-hot, overlap with x) ----
    half8 th[2];
    float wg[4];
    if constexpr (USE_WS) {
#pragma unroll
        for (int kt = 0; kt < 2; ++kt)
            th[kt] = *(const half8*)&ws[64 + ((size_t)((((w << 1) + kt) * 64) + lane)) * 4];
        const float4 wv = *(const float4*)&ws[(w << 4) + (q << 2)];
        wg[0] = wv.x; wg[1] = wv.y; wg[2] = wv.z; wg[3] = wv.w;
    } else {
        const float* tr = theta + (size_t)((w << 4) + c15) * 64 + (q << 3);
#pragma unroll
        for (int kt = 0; kt < 2; ++kt) {
            float4 a = *(const float4*)(tr + kt * 32);
            float4 c = *(const float4*)(tr + kt * 32 + 4);
            a.x *= LOG2E; a.y *= LOG2E; a.z *= LOG2E; a.w *= LOG2E;
            c.x *= LOG2E; c.y *= LOG2E; c.z *= LOG2E; c.w *= LOG2E;
            th[kt] = cvt8(a, c);
        }
        const float mwl = mw[lane];
        float mmax = mwl;
#pragma unroll
        for (int s = 32; s >= 1; s >>= 1) mmax = fmaxf(mmax, __shfl_xor(mmax, s, 64));
        float me = __expf(mwl - mmax);
#pragma unroll
        for (int s = 32; s >= 1; s >>= 1) me += __shfl_xor(me, s, 64);
        const float logZ = mmax + __logf(me);
#pragma unroll
        for (int i = 0; i < 4; ++i)
            wg[i] = (mw[(w << 4) + (q << 2) + i] - logZ) * LOG2E;
    }

    // ---- cvt + stage into LDS ----
#pragma unroll
    for (int i = 0; i < 4; ++i) {
        const int j2 = (i << 8) + tid;   // row = j2>>3, p8 = j2&7
        const half8 h = cvt8(ra[2 * i], ra[2 * i + 1]);
        *(half8*)(xbuf + (j2 >> 3) * 144 + (j2 & 7) * 16) = h;
    }
    __syncthreads();

    // ---- GEMM: 8 N-tiles x 2 K-tiles, single fp16 MFMA each ----
    f32x4 acc[8];
#pragma unroll
    for (int nt = 0; nt < 8; ++nt) acc[nt] = (f32x4){0.f, 0.f, 0.f, 0.f};

#pragma unroll
    for (int nt = 0; nt < 8; ++nt) {
        const unsigned char* rb = xbuf + ((nt << 4) + c15) * 144 + (q << 4);
        const half8 x0 = *(const half8*)(rb);
        const half8 x1 = *(const half8*)(rb + 64);
        acc[nt] = __builtin_amdgcn_mfma_f32_16x16x32_f16(th[0], x0, acc[nt], 0, 0, 0);
        acc[nt] = __builtin_amdgcn_mfma_f32_16x16x32_f16(th[1], x1, acc[nt], 0, 0, 0);
    }

    // ---- p = exp2(util), masked slots exactly 0 (computed ONCE, reused) ----
#pragma unroll
    for (int nt = 0; nt < 8; ++nt) {
        const bool v = ((nt << 4) + c15) < len;
#pragma unroll
        for (int i = 0; i < 4; ++i) {
            const float pv = exp2_fast(acc[nt][i]);
            acc[nt][i] = v ? pv : 0.f;      // acc now holds p
        }
    }

    // ---- phase 1: denom over l per g (in-lane sum + shfl {1,2,4,8}) ----
    float e4[4];
#pragma unroll
    for (int i = 0; i < 4; ++i) {
        float e = 0.f;
#pragma unroll
        for (int nt = 0; nt < 8; ++nt) e += acc[nt][i];
#pragma unroll
        for (int s = 1; s < 16; s <<= 1) e += __shfl_xor(e, s, 64);
        // e4[i] = exp2(wg - lse2) -- the per-g scale factor
        e4[i] = exp2_fast(wg[i] - log2_fast(e));
    }

    // ---- phase 2: s2[nt] = sum_i p[nt][i] * e4[i]; cross-q via shfl ----
#pragma unroll
    for (int nt = 0; nt < 8; ++nt) {
        float s2 = acc[nt][0] * e4[0];
        s2 = fmaf(acc[nt][1], e4[1], s2);
        s2 = fmaf(acc[nt][2], e4[2], s2);
        s2 = fmaf(acc[nt][3], e4[3], s2);
        s2 += __shfl_xor(s2, 16, 64);
        s2 += __shfl_xor(s2, 32, 64);
        if ((nt >> 1) == q) {           // static reg index, predicated write
            red_s[w][(nt << 4) + c15] = s2;
        }
    }
    __syncthreads();

    // ---- final: sum 4 wave-partials per l; log2 -> ln; finite sentinel ----
    if (tid < 128) {
        const int l = tid;
        const float S = red_s[0][l] + red_s[1][l] + red_s[2][l] + red_s[3][l];
        const float o = LN2 * log2_fast(S);
        out[(size_t)b * 128 + l] = (l < len) ? o : NEGV;
    }
}

extern "C" void kernel_launch(void* const* d_in, const int* in_sizes, int n_in,
                              void* d_out, int out_size, void* d_ws, size_t ws_size,
                              hipStream_t stream) {
    const float* x     = (const float*)d_in[0];
    const int*   lens  = (const int*)d_in[1];
    const float* theta = (const float*)d_in[2];
    const float* mw    = (const float*)d_in[3];
    float* out = (float*)d_out;
    const int B = in_sizes[1];  // 8192

    if (ws_size >= (size_t)WS_FLOATS_NEEDED * sizeof(float)) {
        float* ws = (float*)d_ws;
        prep_kernel<<<1, 64, 0, stream>>>(theta, mw, ws);
        mixed_logit_kernel<true><<<B, 256, 0, stream>>>(x, lens, theta, mw, ws, out);
    } else {
        mixed_logit_kernel<false><<<B, 256, 0, stream>>>(x, lens, theta, mw, nullptr, out);
    }
}